// Round 20
// baseline (570.771 us; speedup 1.0000x reference)
//
#include <hip/hip_runtime.h>
#include <math.h>

typedef __attribute__((ext_vector_type(8)))  short short8;
typedef __attribute__((ext_vector_type(4)))  float float4v;
typedef __attribute__((ext_vector_type(16))) float f32x16;
typedef unsigned int u32;

__device__ __forceinline__ unsigned short f2bf(float f) {
    union { float f; unsigned u; } x; x.f = f;
    unsigned r = x.u + 0x7FFFu + ((x.u >> 16) & 1u);
    return (unsigned short)(r >> 16);
}
__device__ __forceinline__ float bf2f(unsigned short u) {
    union { unsigned u; float f; } x; x.u = ((unsigned)u) << 16;
    return x.f;
}

// whole-wave 16B/lane direct global->LDS copy (lds dest = uniform base + lane*16)
__device__ __forceinline__ void gload16(const void* g, void* l) {
    __builtin_amdgcn_global_load_lds(
        (const __attribute__((address_space(1))) u32*)g,
        (__attribute__((address_space(3))) u32*)l, 16, 0, 0);
}

#define HWSZ ((size_t)512 * 512)

// ---------------- input prep: NCHW f32 (Cin=6) -> NHWC8 bf16 hi + lo planes ----------------
__global__ __launch_bounds__(256)
void prep7_k(const float* __restrict__ in, unsigned short* __restrict__ hi,
             unsigned short* __restrict__ lo)
{
    const int idx = blockIdx.x * 256 + threadIdx.x;   // < 2*512*512
    const int b = idx >> 18, rem = idx & 262143;
    const int h = rem >> 9, w = rem & 511;
    unsigned short vh[8], vl[8];
#pragma unroll
    for (int c = 0; c < 8; ++c) {
        float x = (c < 6) ? in[((size_t)(b * 6 + c)) * HWSZ + (h << 9) + w] : 0.f;
        unsigned short h16 = f2bf(x);
        vh[c] = h16;
        vl[c] = f2bf(x - bf2f(h16));
    }
    const size_t o = ((size_t)idx) * 8;
    *(uint4*)(hi + o) = *(uint4*)vh;
    *(uint4*)(lo + o) = *(uint4*)vl;
}

// ---------------- conv7 weight repack: (64,6,7,7) f32 -> fragment-linear bf16 hi/lo ----------------
__global__ __launch_bounds__(256)
void repack7_k(const float* __restrict__ wsrc, unsigned short* __restrict__ dhi,
               unsigned short* __restrict__ dlo)
{
    const int t = blockIdx.x * 256 + threadIdx.x;   // < 26624
    if (t >= 26624) return;
    const int j = t & 7, l = (t >> 3) & 63, ct = (t >> 9) & 3, kk = t >> 11;
    const int co = ct * 16 + (l & 15);
    const int s = kk * 4 + (l >> 4);
    float v = 0.f;
    if (s < 49 && j < 6)
        v = wsrc[((size_t)(co * 6 + j) * 7 + s / 7) * 7 + s % 7];
    unsigned short h16 = f2bf(v);
    dhi[t] = h16;
    dlo[t] = f2bf(v - bf2f(h16));
}

// ---------------- conv 7x7 MFMA implicit GEMM, split precision, + ReLU ----------------
// R12-recipe staging: patch via gload16 (linear LDS), weights hi/lo staged to LDS in
// 7 phases of 2 kk (16.4 KB buffer). LDS = 34304 (patch) + 16384 (weights) = 50688 B
// -> 3 blocks/CU.  out: split-plane NHWC32 bf16 [b][2][512][512][32]
__global__ __launch_bounds__(256)
void conv7_mfma(const unsigned short* __restrict__ inhi,
                const unsigned short* __restrict__ inlo,
                const unsigned short* __restrict__ whi,
                const unsigned short* __restrict__ wlo,
                unsigned short* __restrict__ out)
{
    extern __shared__ char smem[];
    char* p_lds = smem;              // [2 planes][8 rows][134 c][16B] = 34304 B
    char* w_lds = smem + 34304;      // [2 kkrel][2 hl][4 ct][64 l][16B] = 16384 B

    const int id = blockIdx.x;                      // 2048 blocks
    const int lid = (id & 7) * 256 + (id >> 3);     // XCD chunk swizzle
    const int w0 = (lid & 3) * 128;
    const int rest = lid >> 2;
    const int h0 = (rest & 255) * 2;
    const int b  = rest >> 8;

    const int tid = threadIdx.x;
    const int wv = tid >> 6, l = tid & 63, lq = l >> 4, lr = l & 15;

    // ---- patch interior: 2 planes x 8 rows x 2 runs (c=3..66, 67..130) via gload16 ----
    for (int i = wv; i < 32; i += 4) {
        const int run = i & 1, r = (i >> 1) & 7, pl = i >> 4;
        const int hh = h0 - 3 + r;
        if (hh >= 0 && hh < 512) {
            const unsigned short* src = pl ? inlo : inhi;
            gload16(src + ((size_t)((size_t)b * 512 + hh) * 512 + w0 + run * 64 + l) * 8,
                    p_lds + (size_t)((pl * 8 + r) * 134 + 3 + run * 64) * 16);
        }
    }
    // ---- halo cols c in {0,1,2,131,132,133}: 96 granules, predicated (OOB -> zero) ----
    if (tid < 96) {
        const int pl = tid / 48, rem2 = tid % 48;
        const int r = rem2 / 6, c6 = rem2 % 6;
        const int c = (c6 < 3) ? c6 : (128 + c6);
        const int hh = h0 - 3 + r, wc = w0 - 3 + c;
        int4 v = make_int4(0, 0, 0, 0);
        if (hh >= 0 && hh < 512 && wc >= 0 && wc < 512) {
            const unsigned short* src = pl ? inlo : inhi;
            v = *(const int4*)(src + ((size_t)((size_t)b * 512 + hh) * 512 + wc) * 8);
        }
        *(int4*)(p_lds + (size_t)((pl * 8 + r) * 134 + c) * 16) = v;
    }
    // ---- zero interior of out-of-image rows (edge blocks only; gload16 skipped them) ----
    if (h0 <= 2 || h0 >= 508) {
        for (int r = 0; r < 8; ++r) {
            const int hh = h0 - 3 + r;
            if (hh < 0 || hh >= 512) {
                for (int g = tid; g < 268; g += 256) {
                    const int pl = g >= 134, c = pl ? (g - 134) : g;
                    *(int4*)(p_lds + (size_t)((pl * 8 + r) * 134 + c) * 16) = make_int4(0, 0, 0, 0);
                }
            }
        }
    }

    float4v acc[2][2][4];
#pragma unroll
    for (int pr = 0; pr < 2; ++pr)
#pragma unroll
        for (int pb = 0; pb < 2; ++pb)
#pragma unroll
            for (int ct = 0; ct < 4; ++ct)
                acc[pr][pb][ct] = (float4v){0.f, 0.f, 0.f, 0.f};

    const int cbase = wv * 32 + lr;

    for (int ph = 0; ph < 7; ++ph) {
        const int kk0 = ph * 2;
        const int nkk = (ph < 6) ? 2 : 1;
        if (ph) __syncthreads();          // previous compute done reading w_lds

        // ---- stage weights for this phase: nkk x {hi,lo} x 4 ct whole-wave issues ----
        for (int i = wv; i < nkk * 8; i += 4) {
            const int kkrel = i >> 3, hl = (i >> 2) & 1, ct = i & 3;
            const unsigned short* sw = hl ? wlo : whi;
            gload16(sw + ((size_t)((kk0 + kkrel) * 4 + ct) * 64 + l) * 8,
                    w_lds + (size_t)(((kkrel * 2 + hl) * 4 + ct) * 64) * 16);
        }
        __syncthreads();

#pragma unroll
        for (int kkrel = 0; kkrel < 2; ++kkrel) {
            if (kkrel >= nkk) break;
            const int kk = kk0 + kkrel;
            int s = kk * 4 + lq;
            if (s > 48) s = 48;           // padded slots: weights are zero
            const int dh = s / 7, dwd = s % 7;
            short8 ah[2][2], al[2][2];
#pragma unroll
            for (int pr = 0; pr < 2; ++pr)
#pragma unroll
                for (int pb = 0; pb < 2; ++pb) {
                    const int off = ((pr + dh) * 134 + cbase + pb * 16 + dwd) * 16;
                    ah[pr][pb] = *(const short8*)(p_lds + off);
                    al[pr][pb] = *(const short8*)(p_lds + 17152 + off);
                }
#pragma unroll
            for (int ct = 0; ct < 4; ++ct) {
                const short8 bh = *(const short8*)(w_lds +
                    (size_t)(((kkrel * 2 + 0) * 4 + ct) * 64 + l) * 16);
                const short8 bl = *(const short8*)(w_lds +
                    (size_t)(((kkrel * 2 + 1) * 4 + ct) * 64 + l) * 16);
#pragma unroll
                for (int pr = 0; pr < 2; ++pr)
#pragma unroll
                    for (int pb = 0; pb < 2; ++pb) {
                        acc[pr][pb][ct] = __builtin_amdgcn_mfma_f32_16x16x32_bf16(ah[pr][pb], bh, acc[pr][pb][ct], 0, 0, 0);
                        acc[pr][pb][ct] = __builtin_amdgcn_mfma_f32_16x16x32_bf16(al[pr][pb], bh, acc[pr][pb][ct], 0, 0, 0);
                        acc[pr][pb][ct] = __builtin_amdgcn_mfma_f32_16x16x32_bf16(ah[pr][pb], bl, acc[pr][pb][ct], 0, 0, 0);
                    }
            }
        }
    }

#pragma unroll
    for (int pr = 0; pr < 2; ++pr) {
        const int h = h0 + pr;
#pragma unroll
        for (int pb = 0; pb < 2; ++pb) {
            const int col0 = w0 + wv * 32 + pb * 16 + lq * 4;
#pragma unroll
            for (int ct = 0; ct < 4; ++ct) {
                const int half = ct >> 1, colocal = (ct & 1) * 16 + lr;
#pragma unroll
                for (int rg = 0; rg < 4; ++rg) {
                    const size_t o = ((((size_t)(b * 2 + half) * 512 + h) * 512) + (col0 + rg)) * 32 + colocal;
                    out[o] = f2bf(fmaxf(acc[pr][pb][ct][rg], 0.f));
                }
            }
        }
    }
}

// ---------------- conv3 weight repack for 32x32x16 path: fold BN scale, QUARTER-major ----------
__global__ __launch_bounds__(256)
void repack3n_k(const float* __restrict__ w1, const float* __restrict__ w2,
                const float* __restrict__ g1, const float* __restrict__ v1,
                const float* __restrict__ g2, const float* __restrict__ v2,
                unsigned short* __restrict__ dst)
{
    const int conv = blockIdx.z;
    const float* src = (conv < 4) ? (w1 + (size_t)conv * 36864) : (w2 + (size_t)(conv - 4) * 36864);
    const float* g = (conv < 4) ? (g1 + conv * 64) : (g2 + (conv - 4) * 64);
    const float* vv = (conv < 4) ? (v1 + conv * 64) : (v2 + (conv - 4) * 64);
    unsigned short* d = dst + (size_t)conv * 36864;

    const int t = blockIdx.x * 256 + threadIdx.x;   // < 36864
    const int j = t & 7, l = (t >> 3) & 63;
    const int rest = t >> 9;         // 0..71
    const int s = rest % 9, m = rest / 9;
    const int ch = m & 1, q = m >> 1;
    const int co = ch * 32 + (l & 31);
    const int ci = q * 16 + (l >> 5) * 8 + j;
    const float sc = g[co] * rsqrtf(vv[co] + 1e-5f);
    d[t] = f2bf(src[((size_t)co * 64 + ci) * 9 + s] * sc);
}

// bias table: bias[conv][co] = beta - mean * scale
__global__ __launch_bounds__(256)
void bias8_k(const float* __restrict__ g1, const float* __restrict__ b1,
             const float* __restrict__ m1, const float* __restrict__ v1,
             const float* __restrict__ g2, const float* __restrict__ b2,
             const float* __restrict__ m2, const float* __restrict__ v2,
             float* __restrict__ bias)
{
    const int t = blockIdx.x * 256 + threadIdx.x;   // < 512
    if (t >= 512) return;
    const int conv = t >> 6, co = t & 63;
    const float* g = (conv < 4) ? (g1 + conv * 64) : (g2 + (conv - 4) * 64);
    const float* be = (conv < 4) ? (b1 + conv * 64) : (b2 + (conv - 4) * 64);
    const float* mn = (conv < 4) ? (m1 + conv * 64) : (m2 + (conv - 4) * 64);
    const float* vv = (conv < 4) ? (v1 + conv * 64) : (v2 + (conv - 4) * 64);
    const float sc = g[co] * rsqrtf(vv[co] + 1e-5f);
    bias[t] = be[co] - mn[co] * sc;
}

// ---------------- conv 3x3 implicit-GEMM, 32x32x16 MFMA, ci-quarter 4-phase ----------------
// SMALL-BLOCK variant of R13: 256 thr (4 waves, rw = wv = row 0..3), tile 4 rows x 64 px.
// LDS: weights [2ch][9s][64l][16B]=18432 + patch [12 plane][68 g][16B]=13056 -> 31488 B.
// VGPR ~96 -> 5 waves/SIMD -> 5 blocks/CU (20 waves, 25% more than R13's 16) and 5
// independent stage/compute pipelines per CU. Same per-wave work/order as R13.
template <bool ADD_>
__global__ __launch_bounds__(256)
void conv3_mfma32(const unsigned short* __restrict__ in,
                  const unsigned short* __restrict__ wrp,
                  const float* __restrict__ bias,
                  const unsigned short* __restrict__ skip,
                  unsigned short* __restrict__ out)
{
    extern __shared__ char smem[];
    char* w_lds = smem;              // 18432 B
    char* p_lds = smem + 18432;      // 13056 B

    const int id = blockIdx.x;                      // 2048 blocks
    const int lid = (id & 7) * 256 + (id >> 3);     // XCD chunk swizzle
    const int w0 = (lid & 7) * 64;
    const int h0 = ((lid >> 3) & 127) * 4;
    const int b  = lid >> 10;

    const int tid = threadIdx.x;
    const int wv = tid >> 6, l = tid & 63;
    const int rw = wv;                               // output row 0..3
    const int lo5 = l & 31, hi = l >> 5;

    f32x16 acc[2][2];   // [ch][t4]
#pragma unroll
    for (int ch = 0; ch < 2; ++ch)
#pragma unroll
        for (int t4 = 0; t4 < 2; ++t4)
#pragma unroll
            for (int e = 0; e < 16; ++e) acc[ch][t4][e] = 0.f;

    for (int q = 0; q < 4; ++q) {
        if (q) __syncthreads();   // previous phase's LDS fully consumed

        const unsigned short* wq  = wrp + (size_t)q * 9216;
        const unsigned short* inp = in + (size_t)(b * 2 + (q >> 1)) * HWSZ * 32;
        const int cb8 = (q & 1) * 2;

        // ---- whole-wave gload16 staging: 18 weight + 12 patch-interior issues ----
        for (int i = wv; i < 30; i += 4) {
            if (i < 18) {
                gload16(wq + (size_t)i * 512 + l * 8, w_lds + (size_t)i * 1024);
            } else {
                const int p = i - 18;               // plane 0..11
                const int row = p >> 1, kg = p & 1;
                const int hh = h0 - 1 + row;
                if (hh >= 0 && hh < 512)
                    gload16(inp + ((size_t)hh * 512 + w0 + l) * 32 + (cb8 + kg) * 8,
                            p_lds + (size_t)(p * 68 + 1) * 16);
            }
        }
        // ---- halo granules g=0 (wc=w0-1) and g=65 (wc=w0+64), 24 total ----
        if (tid < 24) {
            const int p = tid >> 1, side = tid & 1;
            const int row = p >> 1, kg = p & 1;
            const int hh = h0 - 1 + row;
            const int wc = side ? (w0 + 64) : (w0 - 1);
            int4 v = make_int4(0, 0, 0, 0);
            if (hh >= 0 && hh < 512 && wc >= 0 && wc < 512)
                v = *(const int4*)(inp + ((size_t)hh * 512 + wc) * 32 + (cb8 + kg) * 8);
            *(int4*)(p_lds + (size_t)(p * 68 + (side ? 65 : 0)) * 16) = v;
        }
        // ---- out-of-image rows: zero both planes of the OOB row (edge blocks only) ----
        if (h0 == 0) {
            if (tid < 136) {                         // planes 0,1 (row -1)
                const int pl2 = tid >= 68, c = tid - pl2 * 68;
                *(int4*)(p_lds + (size_t)(pl2 * 68 + c) * 16) = make_int4(0, 0, 0, 0);
            }
        } else if (h0 == 508) {
            if (tid < 136) {                         // planes 10,11 (row +4)
                const int pl2 = tid >= 68, c = tid - pl2 * 68;
                *(int4*)(p_lds + (size_t)((10 + pl2) * 68 + c) * 16) = make_int4(0, 0, 0, 0);
            }
        }
        __syncthreads();

        // ---- K-loop: 9 slots; 1 A-read feeds both ch MFMAs; kg = hi ----
#pragma unroll
        for (int s = 0; s < 9; ++s) {
            const int dh = s / 3, dwd = s % 3;
            const int row = rw + dh;
            short8 pf[2];
#pragma unroll
            for (int t4 = 0; t4 < 2; ++t4) {
                const int px = t4 * 32 + dwd + lo5;
                pf[t4] = *(const short8*)(p_lds +
                    ((size_t)((row * 2 + hi) * 68 + px)) * 16);
            }
#pragma unroll
            for (int ch = 0; ch < 2; ++ch) {
                const short8 w8 = *(const short8*)(w_lds +
                    ((size_t)((ch * 9 + s) * 64 + l)) * 16);
#pragma unroll
                for (int t4 = 0; t4 < 2; ++t4)
                    acc[ch][t4] = __builtin_amdgcn_mfma_f32_32x32x16_bf16(
                        pf[t4], w8, acc[ch][t4], 0, 0, 0);
            }
        }
    }

    // ---- epilogue: D col = l&31 = co_local; 32 lanes = one pixel's contiguous 64 B ----
    const int h = h0 + rw;
#pragma unroll
    for (int ch = 0; ch < 2; ++ch) {
        const float bvs = bias[ch * 32 + lo5];
        const size_t pbase = ((size_t)(b * 2 + ch) * HWSZ + (size_t)h * 512);
#pragma unroll
        for (int t4 = 0; t4 < 2; ++t4) {
#pragma unroll
            for (int reg = 0; reg < 16; ++reg) {
                const int pxl = t4 * 32 + (reg & 3) + 8 * (reg >> 2) + 4 * hi;
                const size_t o = (pbase + (w0 + pxl)) * 32 + lo5;
                float v = fmaxf(acc[ch][t4][reg] + bvs, 0.f);
                if (ADD_) v += bf2f(skip[o]);
                out[o] = f2bf(v);
            }
        }
    }
}

// ---------------- conv_last weight repack: A-operand fragment-linear, quarter-major ----------
__global__ __launch_bounds__(256)
void repackLn_k(const float* __restrict__ wsrc, unsigned short* __restrict__ d)
{
    const int t = blockIdx.x * 256 + threadIdx.x;   // < 18432
    const int j = t & 7, l = (t >> 3) & 63;
    const int rest = t >> 9;           // 0..35
    const int s = rest % 9, q = rest / 9;
    const int co = l & 31;
    const int ci = q * 16 + (l >> 5) * 8 + j;
    d[t] = (co < 30) ? f2bf(wsrc[((size_t)co * 64 + ci) * 9 + s]) : (unsigned short)0;
}

// ---------------- conv_last: 32x32x16 MFMA, A=weights(LDS) B=pixels(LDS), 4-phase ----------
__global__ __launch_bounds__(256)
void conv_lastN(const unsigned short* __restrict__ in,
                const unsigned short* __restrict__ wrp,
                unsigned short* __restrict__ out)
{
    extern __shared__ char smem[];
    char* w_lds = smem;              // 36864 B
    char* p_lds = smem + 36864;      // 16896 B

    const int id = blockIdx.x;                      // 2048 blocks
    const int lid = (id & 7) * 256 + (id >> 3);     // XCD chunk swizzle
    const int w0 = (lid & 3) * 128;
    const int h0 = ((lid >> 2) & 255) * 2;
    const int b  = lid >> 10;

    const int tid = threadIdx.x;
    const int wv = tid >> 6, l = tid & 63;
    const int rw = wv >> 1, tq = wv & 1;
    const int lo5 = l & 31, hi = l >> 5;

    f32x16 acc[2];
#pragma unroll
    for (int t4 = 0; t4 < 2; ++t4)
#pragma unroll
        for (int e = 0; e < 16; ++e) acc[t4][e] = 0.f;

    for (int q = 0; q < 4; ++q) {
        if (q) __syncthreads();

        const unsigned short* inp = in + (size_t)(b * 2 + (q >> 1)) * HWSZ * 32;
        const int cb8 = (q & 1) * 2;

        if (q == 0)
            for (int i = wv; i < 36; i += 4)
                gload16(wrp + (size_t)i * 512 + l * 8, w_lds + (size_t)i * 1024);
        for (int i = wv; i < 16; i += 4) {
            const int p = i >> 1, half = i & 1;
            const int row = p >> 1, kg = p & 1;
            const int hh = h0 - 1 + row;
            if (hh >= 0 && hh < 512)
                gload16(inp + ((size_t)hh * 512 + w0 + half * 64 + l) * 32 + (cb8 + kg) * 8,
                        p_lds + (size_t)(p * 132 + 1 + half * 64) * 16);
        }
        if (tid < 16) {
            const int p = tid >> 1, side = tid & 1;
            const int row = p >> 1, kg = p & 1;
            const int hh = h0 - 1 + row;
            const int wc = side ? (w0 + 128) : (w0 - 1);
            int4 v = make_int4(0, 0, 0, 0);
            if (hh >= 0 && hh < 512 && wc >= 0 && wc < 512)
                v = *(const int4*)(inp + ((size_t)hh * 512 + wc) * 32 + (cb8 + kg) * 8);
            *(int4*)(p_lds + (size_t)(p * 132 + (side ? 129 : 0)) * 16) = v;
        }
        if (h0 == 0) {
            for (int g = tid; g < 264; g += 256)
                *(int4*)(p_lds + (size_t)g * 16) = make_int4(0, 0, 0, 0);
        } else if (h0 == 510) {
            for (int g = tid; g < 264; g += 256)
                *(int4*)(p_lds + (size_t)(6 * 132 + g) * 16) = make_int4(0, 0, 0, 0);
        }
        __syncthreads();

#pragma unroll
        for (int s = 0; s < 9; ++s) {
            const int dh = s / 3, dwd = s % 3;
            const int row = rw + dh;
            const short8 wf = *(const short8*)(w_lds + ((size_t)((q * 9 + s) * 64 + l)) * 16);
#pragma unroll
            for (int t4 = 0; t4 < 2; ++t4) {
                const int px = tq * 64 + t4 * 32 + dwd + lo5;
                const short8 pf = *(const short8*)(p_lds +
                    ((size_t)((row * 2 + hi) * 132 + px)) * 16);
                acc[t4] = __builtin_amdgcn_mfma_f32_32x32x16_bf16(wf, pf, acc[t4], 0, 0, 0);
            }
        }
    }

    const int h = h0 + rw;
#pragma unroll
    for (int t4 = 0; t4 < 2; ++t4) {
        const int px = w0 + tq * 64 + t4 * 32 + lo5;
#pragma unroll
        for (int reg = 0; reg < 16; ++reg) {
            const int co = (reg & 3) + 8 * (reg >> 2) + 4 * hi;
            if (co < 30)
                out[(((size_t)(b * 30 + co) * 512 + h) * 512) + px] = f2bf(acc[t4][reg]);
        }
    }
}

// ---------------- fused adaptive filter ----------------
__global__ __launch_bounds__(256)
void filt_fused_k(const unsigned short* __restrict__ wl, const float* __restrict__ base,
                  float* __restrict__ out)
{
    __shared__ float F[516];

    const int id = blockIdx.x;                      // 3072 blocks
    const int lid = (id & 7) * 384 + (id >> 3);
    const int h = lid & 511;
    const int bc = lid >> 9;
    const int b = bc / 3, c = bc % 3;
    const int t = threadIdx.x;

    if (t < 2) F[t] = 0.f;
    if (t >= 254) F[t + 260] = 0.f;

    const size_t rowoff = (size_t)h * 512;
    const unsigned short* wv_p = wl + ((size_t)(b * 30 + c * 10) * HWSZ) + rowoff;
    const unsigned short* wh_p = wv_p + 5 * HWSZ;
    const float* bp = base + (size_t)bc * HWSZ;

#pragma unroll
    for (int wi = 0; wi < 2; ++wi) {
        const int w = t + wi * 256;
        float v[5]; float mx = -1e30f;
#pragma unroll
        for (int i = 0; i < 5; ++i) { v[i] = bf2f(wv_p[(size_t)i * HWSZ + w]); mx = fmaxf(mx, v[i]); }
        float sm = 0.f;
#pragma unroll
        for (int i = 0; i < 5; ++i) { v[i] = __expf(v[i] - mx); sm += v[i]; }
        const float inv = 1.f / sm;
        float acc = 0.f;
#pragma unroll
        for (int i = 0; i < 5; ++i) {
            const int hh = h + i - 2;
            const float bvv = (hh >= 0 && hh < 512) ? bp[(size_t)hh * 512 + w] : 0.f;
            acc = fmaf(bvv, v[i] * inv, acc);
        }
        F[w + 2] = acc;
    }
    __syncthreads();

#pragma unroll
    for (int wi = 0; wi < 2; ++wi) {
        const int w = t + wi * 256;
        float v[5]; float mx = -1e30f;
#pragma unroll
        for (int i = 0; i < 5; ++i) { v[i] = bf2f(wh_p[(size_t)i * HWSZ + w]); mx = fmaxf(mx, v[i]); }
        float sm = 0.f;
#pragma unroll
        for (int i = 0; i < 5; ++i) { v[i] = __expf(v[i] - mx); sm += v[i]; }
        const float inv = 1.f / sm;
        float acc = 0.f;
#pragma unroll
        for (int i = 0; i < 5; ++i)
            acc = fmaf(F[w + i], v[i] * inv, acc);
        out[(size_t)bc * HWSZ + rowoff + w] = acc;
    }
}

extern "C" void kernel_launch(void* const* d_in, const int* in_sizes, int n_in,
                              void* d_out, int out_size, void* d_ws, size_t ws_size,
                              hipStream_t stream)
{
    const float* fm      = (const float*)d_in[0];
    const float* base    = (const float*)d_in[1];
    const float* w_first = (const float*)d_in[2];
    const float* kb_w1   = (const float*)d_in[3];
    const float* kb_g1   = (const float*)d_in[4];
    const float* kb_b1   = (const float*)d_in[5];
    const float* kb_m1   = (const float*)d_in[6];
    const float* kb_v1   = (const float*)d_in[7];
    const float* kb_w2   = (const float*)d_in[8];
    const float* kb_g2   = (const float*)d_in[9];
    const float* kb_b2   = (const float*)d_in[10];
    const float* kb_m2   = (const float*)d_in[11];
    const float* kb_v2   = (const float*)d_in[12];
    const float* w_last  = (const float*)d_in[13];

    char* ws = (char*)d_ws;
    unsigned short* wrp3n  = (unsigned short*)ws;                 // 8*36864 bf16 = 589824 B
    unsigned short* wrpL   = wrp3n + (size_t)8 * 36864;           // 36864 B
    unsigned short* wrp7hi = wrpL + 18432;                        // 53248 B
    unsigned short* wrp7lo = wrp7hi + 26624;                      // 53248 B
    float*          biasws = (float*)(wrp7lo + 26624);            // 2048 B
    unsigned short* actA = (unsigned short*)(ws + (1 << 20));     // 67 MB each, split-plane NHWC32
    unsigned short* actB = actA + (size_t)2 * HWSZ * 64;
    unsigned short* actC = actB + (size_t)2 * HWSZ * 64;
    unsigned short* in7hi = actB;                                 // dead once conv7 done
    unsigned short* in7lo = actB + (size_t)2 * HWSZ * 8;
    unsigned short* logits = actC;                                // planar30; actC free by then

    hipFuncSetAttribute((const void*)conv3_mfma32<false>,
                        hipFuncAttributeMaxDynamicSharedMemorySize, 31488);
    hipFuncSetAttribute((const void*)conv3_mfma32<true>,
                        hipFuncAttributeMaxDynamicSharedMemorySize, 31488);
    hipFuncSetAttribute((const void*)conv_lastN,
                        hipFuncAttributeMaxDynamicSharedMemorySize, 53760);
    hipFuncSetAttribute((const void*)conv7_mfma,
                        hipFuncAttributeMaxDynamicSharedMemorySize, 50688);

    dim3 blk(256);

    // weight repacks + input prep
    repack3n_k<<<dim3(144, 1, 8), blk, 0, stream>>>(kb_w1, kb_w2, kb_g1, kb_v1, kb_g2, kb_v2, wrp3n);
    bias8_k<<<dim3(2, 1, 1), blk, 0, stream>>>(kb_g1, kb_b1, kb_m1, kb_v1, kb_g2, kb_b2, kb_m2, kb_v2, biasws);
    repackLn_k<<<dim3(72, 1, 1), blk, 0, stream>>>(w_last, wrpL);
    repack7_k<<<dim3(104, 1, 1), blk, 0, stream>>>(w_first, wrp7hi, wrp7lo);
    prep7_k<<<dim3(2048, 1, 1), blk, 0, stream>>>(fm, in7hi, in7lo);

    // conv_first -> actA
    conv7_mfma<<<dim3(2048, 1, 1), blk, 50688, stream>>>(in7hi, in7lo, wrp7hi, wrp7lo, actA);

    // residual blocks (small-block conv3: 4x64 tiles, 5 blocks/CU)
    unsigned short* cur = actA;
    unsigned short* oth = actC;
    for (int i = 0; i < 4; ++i) {
        conv3_mfma32<false><<<dim3(2048, 1, 1), blk, 31488, stream>>>(
            cur, wrp3n + (size_t)i * 36864, biasws + i * 64, nullptr, actB);
        conv3_mfma32<true><<<dim3(2048, 1, 1), blk, 31488, stream>>>(
            actB, wrp3n + (size_t)(4 + i) * 36864, biasws + (4 + i) * 64, cur, oth);
        unsigned short* t = cur; cur = oth; oth = t;
    }

    // conv_last: 64 -> 30, planar30 bf16 logits
    conv_lastN<<<dim3(2048, 1, 1), blk, 53760, stream>>>(cur, wrpL, logits);

    // fused adaptive filtering
    filt_fused_k<<<dim3(3072, 1, 1), blk, 0, stream>>>(logits, base, (float*)d_out);
}

// Round 21
// 536.093 us; speedup vs baseline: 1.0647x; 1.0647x over previous
//
#include <hip/hip_runtime.h>
#include <math.h>

typedef __attribute__((ext_vector_type(8)))  short short8;
typedef __attribute__((ext_vector_type(4)))  float float4v;
typedef __attribute__((ext_vector_type(16))) float f32x16;
typedef unsigned int u32;

__device__ __forceinline__ unsigned short f2bf(float f) {
    union { float f; unsigned u; } x; x.f = f;
    unsigned r = x.u + 0x7FFFu + ((x.u >> 16) & 1u);
    return (unsigned short)(r >> 16);
}
__device__ __forceinline__ float bf2f(unsigned short u) {
    union { unsigned u; float f; } x; x.u = ((unsigned)u) << 16;
    return x.f;
}

// whole-wave 16B/lane direct global->LDS copy (lds dest = uniform base + lane*16)
__device__ __forceinline__ void gload16(const void* g, void* l) {
    __builtin_amdgcn_global_load_lds(
        (const __attribute__((address_space(1))) u32*)g,
        (__attribute__((address_space(3))) u32*)l, 16, 0, 0);
}

#define HWSZ ((size_t)512 * 512)

// ---------------- input prep: NCHW f32 (Cin=6) -> NHWC8 bf16 hi + lo planes ----------------
__global__ __launch_bounds__(256)
void prep7_k(const float* __restrict__ in, unsigned short* __restrict__ hi,
             unsigned short* __restrict__ lo)
{
    const int idx = blockIdx.x * 256 + threadIdx.x;   // < 2*512*512
    const int b = idx >> 18, rem = idx & 262143;
    const int h = rem >> 9, w = rem & 511;
    unsigned short vh[8], vl[8];
#pragma unroll
    for (int c = 0; c < 8; ++c) {
        float x = (c < 6) ? in[((size_t)(b * 6 + c)) * HWSZ + (h << 9) + w] : 0.f;
        unsigned short h16 = f2bf(x);
        vh[c] = h16;
        vl[c] = f2bf(x - bf2f(h16));
    }
    const size_t o = ((size_t)idx) * 8;
    *(uint4*)(hi + o) = *(uint4*)vh;
    *(uint4*)(lo + o) = *(uint4*)vl;
}

// ---------------- conv7 weight repack: (64,6,7,7) f32 -> fragment-linear bf16 hi/lo ----------------
__global__ __launch_bounds__(256)
void repack7_k(const float* __restrict__ wsrc, unsigned short* __restrict__ dhi,
               unsigned short* __restrict__ dlo)
{
    const int t = blockIdx.x * 256 + threadIdx.x;   // < 26624
    if (t >= 26624) return;
    const int j = t & 7, l = (t >> 3) & 63, ct = (t >> 9) & 3, kk = t >> 11;
    const int co = ct * 16 + (l & 15);
    const int s = kk * 4 + (l >> 4);
    float v = 0.f;
    if (s < 49 && j < 6)
        v = wsrc[((size_t)(co * 6 + j) * 7 + s / 7) * 7 + s % 7];
    unsigned short h16 = f2bf(v);
    dhi[t] = h16;
    dlo[t] = f2bf(v - bf2f(h16));
}

// ---------------- conv 7x7 MFMA implicit GEMM, split precision, + ReLU ----------------
// R12-recipe staging: patch via gload16 (linear LDS), weights hi/lo staged to LDS in
// 7 phases of 2 kk (16.4 KB buffer). LDS = 34304 (patch) + 16384 (weights) = 50688 B
// -> 3 blocks/CU.  out: split-plane NHWC32 bf16 [b][2][512][512][32]
__global__ __launch_bounds__(256)
void conv7_mfma(const unsigned short* __restrict__ inhi,
                const unsigned short* __restrict__ inlo,
                const unsigned short* __restrict__ whi,
                const unsigned short* __restrict__ wlo,
                unsigned short* __restrict__ out)
{
    extern __shared__ char smem[];
    char* p_lds = smem;              // [2 planes][8 rows][134 c][16B] = 34304 B
    char* w_lds = smem + 34304;      // [2 kkrel][2 hl][4 ct][64 l][16B] = 16384 B

    const int id = blockIdx.x;                      // 2048 blocks
    const int lid = (id & 7) * 256 + (id >> 3);     // XCD chunk swizzle
    const int w0 = (lid & 3) * 128;
    const int rest = lid >> 2;
    const int h0 = (rest & 255) * 2;
    const int b  = rest >> 8;

    const int tid = threadIdx.x;
    const int wv = tid >> 6, l = tid & 63, lq = l >> 4, lr = l & 15;

    // ---- patch interior: 2 planes x 8 rows x 2 runs (c=3..66, 67..130) via gload16 ----
    for (int i = wv; i < 32; i += 4) {
        const int run = i & 1, r = (i >> 1) & 7, pl = i >> 4;
        const int hh = h0 - 3 + r;
        if (hh >= 0 && hh < 512) {
            const unsigned short* src = pl ? inlo : inhi;
            gload16(src + ((size_t)((size_t)b * 512 + hh) * 512 + w0 + run * 64 + l) * 8,
                    p_lds + (size_t)((pl * 8 + r) * 134 + 3 + run * 64) * 16);
        }
    }
    // ---- halo cols c in {0,1,2,131,132,133}: 96 granules, predicated (OOB -> zero) ----
    if (tid < 96) {
        const int pl = tid / 48, rem2 = tid % 48;
        const int r = rem2 / 6, c6 = rem2 % 6;
        const int c = (c6 < 3) ? c6 : (128 + c6);
        const int hh = h0 - 3 + r, wc = w0 - 3 + c;
        int4 v = make_int4(0, 0, 0, 0);
        if (hh >= 0 && hh < 512 && wc >= 0 && wc < 512) {
            const unsigned short* src = pl ? inlo : inhi;
            v = *(const int4*)(src + ((size_t)((size_t)b * 512 + hh) * 512 + wc) * 8);
        }
        *(int4*)(p_lds + (size_t)((pl * 8 + r) * 134 + c) * 16) = v;
    }
    // ---- zero interior of out-of-image rows (edge blocks only; gload16 skipped them) ----
    if (h0 <= 2 || h0 >= 508) {
        for (int r = 0; r < 8; ++r) {
            const int hh = h0 - 3 + r;
            if (hh < 0 || hh >= 512) {
                for (int g = tid; g < 268; g += 256) {
                    const int pl = g >= 134, c = pl ? (g - 134) : g;
                    *(int4*)(p_lds + (size_t)((pl * 8 + r) * 134 + c) * 16) = make_int4(0, 0, 0, 0);
                }
            }
        }
    }

    float4v acc[2][2][4];
#pragma unroll
    for (int pr = 0; pr < 2; ++pr)
#pragma unroll
        for (int pb = 0; pb < 2; ++pb)
#pragma unroll
            for (int ct = 0; ct < 4; ++ct)
                acc[pr][pb][ct] = (float4v){0.f, 0.f, 0.f, 0.f};

    const int cbase = wv * 32 + lr;

    for (int ph = 0; ph < 7; ++ph) {
        const int kk0 = ph * 2;
        const int nkk = (ph < 6) ? 2 : 1;
        if (ph) __syncthreads();          // previous compute done reading w_lds

        // ---- stage weights for this phase: nkk x {hi,lo} x 4 ct whole-wave issues ----
        for (int i = wv; i < nkk * 8; i += 4) {
            const int kkrel = i >> 3, hl = (i >> 2) & 1, ct = i & 3;
            const unsigned short* sw = hl ? wlo : whi;
            gload16(sw + ((size_t)((kk0 + kkrel) * 4 + ct) * 64 + l) * 8,
                    w_lds + (size_t)(((kkrel * 2 + hl) * 4 + ct) * 64) * 16);
        }
        __syncthreads();

#pragma unroll
        for (int kkrel = 0; kkrel < 2; ++kkrel) {
            if (kkrel >= nkk) break;
            const int kk = kk0 + kkrel;
            int s = kk * 4 + lq;
            if (s > 48) s = 48;           // padded slots: weights are zero
            const int dh = s / 7, dwd = s % 7;
            short8 ah[2][2], al[2][2];
#pragma unroll
            for (int pr = 0; pr < 2; ++pr)
#pragma unroll
                for (int pb = 0; pb < 2; ++pb) {
                    const int off = ((pr + dh) * 134 + cbase + pb * 16 + dwd) * 16;
                    ah[pr][pb] = *(const short8*)(p_lds + off);
                    al[pr][pb] = *(const short8*)(p_lds + 17152 + off);
                }
#pragma unroll
            for (int ct = 0; ct < 4; ++ct) {
                const short8 bh = *(const short8*)(w_lds +
                    (size_t)(((kkrel * 2 + 0) * 4 + ct) * 64 + l) * 16);
                const short8 bl = *(const short8*)(w_lds +
                    (size_t)(((kkrel * 2 + 1) * 4 + ct) * 64 + l) * 16);
#pragma unroll
                for (int pr = 0; pr < 2; ++pr)
#pragma unroll
                    for (int pb = 0; pb < 2; ++pb) {
                        acc[pr][pb][ct] = __builtin_amdgcn_mfma_f32_16x16x32_bf16(ah[pr][pb], bh, acc[pr][pb][ct], 0, 0, 0);
                        acc[pr][pb][ct] = __builtin_amdgcn_mfma_f32_16x16x32_bf16(al[pr][pb], bh, acc[pr][pb][ct], 0, 0, 0);
                        acc[pr][pb][ct] = __builtin_amdgcn_mfma_f32_16x16x32_bf16(ah[pr][pb], bl, acc[pr][pb][ct], 0, 0, 0);
                    }
            }
        }
    }

#pragma unroll
    for (int pr = 0; pr < 2; ++pr) {
        const int h = h0 + pr;
#pragma unroll
        for (int pb = 0; pb < 2; ++pb) {
            const int col0 = w0 + wv * 32 + pb * 16 + lq * 4;
#pragma unroll
            for (int ct = 0; ct < 4; ++ct) {
                const int half = ct >> 1, colocal = (ct & 1) * 16 + lr;
#pragma unroll
                for (int rg = 0; rg < 4; ++rg) {
                    const size_t o = ((((size_t)(b * 2 + half) * 512 + h) * 512) + (col0 + rg)) * 32 + colocal;
                    out[o] = f2bf(fmaxf(acc[pr][pb][ct][rg], 0.f));
                }
            }
        }
    }
}

// ---------------- conv3 weight repack for 32x32x16 path: fold BN scale, QUARTER-major ----------
__global__ __launch_bounds__(256)
void repack3n_k(const float* __restrict__ w1, const float* __restrict__ w2,
                const float* __restrict__ g1, const float* __restrict__ v1,
                const float* __restrict__ g2, const float* __restrict__ v2,
                unsigned short* __restrict__ dst)
{
    const int conv = blockIdx.z;
    const float* src = (conv < 4) ? (w1 + (size_t)conv * 36864) : (w2 + (size_t)(conv - 4) * 36864);
    const float* g = (conv < 4) ? (g1 + conv * 64) : (g2 + (conv - 4) * 64);
    const float* vv = (conv < 4) ? (v1 + conv * 64) : (v2 + (conv - 4) * 64);
    unsigned short* d = dst + (size_t)conv * 36864;

    const int t = blockIdx.x * 256 + threadIdx.x;   // < 36864
    const int j = t & 7, l = (t >> 3) & 63;
    const int rest = t >> 9;         // 0..71
    const int s = rest % 9, m = rest / 9;
    const int ch = m & 1, q = m >> 1;
    const int co = ch * 32 + (l & 31);
    const int ci = q * 16 + (l >> 5) * 8 + j;
    const float sc = g[co] * rsqrtf(vv[co] + 1e-5f);
    d[t] = f2bf(src[((size_t)co * 64 + ci) * 9 + s] * sc);
}

// bias table: bias[conv][co] = beta - mean * scale
__global__ __launch_bounds__(256)
void bias8_k(const float* __restrict__ g1, const float* __restrict__ b1,
             const float* __restrict__ m1, const float* __restrict__ v1,
             const float* __restrict__ g2, const float* __restrict__ b2,
             const float* __restrict__ m2, const float* __restrict__ v2,
             float* __restrict__ bias)
{
    const int t = blockIdx.x * 256 + threadIdx.x;   // < 512
    if (t >= 512) return;
    const int conv = t >> 6, co = t & 63;
    const float* g = (conv < 4) ? (g1 + conv * 64) : (g2 + (conv - 4) * 64);
    const float* be = (conv < 4) ? (b1 + conv * 64) : (b2 + (conv - 4) * 64);
    const float* mn = (conv < 4) ? (m1 + conv * 64) : (m2 + (conv - 4) * 64);
    const float* vv = (conv < 4) ? (v1 + conv * 64) : (v2 + (conv - 4) * 64);
    const float sc = g[co] * rsqrtf(vv[co] + 1e-5f);
    bias[t] = be[co] - mn[co] * sc;
}

// ---------------- conv 3x3 implicit-GEMM, 32x32x16 MFMA, ci-quarter 4-phase (R13 config) ----
// Staging via global_load_lds; tile 4 rows x 128 px, 512 thr (8 waves: rw=wv>>1, tq=wv&1).
// LDS: weights 18432 + patch 25344 = 43776 B -> 2 blocks/CU.  No min-waves bound (R16 spill).
template <bool ADD_>
__global__ __launch_bounds__(512)
void conv3_mfma32(const unsigned short* __restrict__ in,
                  const unsigned short* __restrict__ wrp,
                  const float* __restrict__ bias,
                  const unsigned short* __restrict__ skip,
                  unsigned short* __restrict__ out)
{
    extern __shared__ char smem[];
    char* w_lds = smem;              // 18432 B
    char* p_lds = smem + 18432;      // 25344 B

    const int id = blockIdx.x;                      // 1024 blocks
    const int lid = (id & 7) * 128 + (id >> 3);     // XCD chunk swizzle
    const int w0 = (lid & 3) * 128;
    const int h0 = ((lid >> 2) & 127) * 4;
    const int b  = lid >> 9;

    const int tid = threadIdx.x;
    const int wv = tid >> 6, l = tid & 63;
    const int rw = wv >> 1, tq = wv & 1;
    const int lo5 = l & 31, hi = l >> 5;

    f32x16 acc[2][2];   // [ch][t4]
#pragma unroll
    for (int ch = 0; ch < 2; ++ch)
#pragma unroll
        for (int t4 = 0; t4 < 2; ++t4)
#pragma unroll
            for (int e = 0; e < 16; ++e) acc[ch][t4][e] = 0.f;

    for (int q = 0; q < 4; ++q) {
        if (q) __syncthreads();   // previous phase's LDS fully consumed

        const unsigned short* wq  = wrp + (size_t)q * 9216;
        const unsigned short* inp = in + (size_t)(b * 2 + (q >> 1)) * HWSZ * 32;
        const int cb8 = (q & 1) * 2;

        // ---- whole-wave global_load_lds staging: 18 weight + 24 patch-interior issues ----
        for (int i = wv; i < 42; i += 8) {
            if (i < 18) {
                gload16(wq + (size_t)i * 512 + l * 8, w_lds + (size_t)i * 1024);
            } else {
                const int j2 = i - 18, p = j2 >> 1, half = j2 & 1;
                const int row = p >> 1, kg = p & 1;
                const int hh = h0 - 1 + row;
                if (hh >= 0 && hh < 512)
                    gload16(inp + ((size_t)hh * 512 + w0 + half * 64 + l) * 32 + (cb8 + kg) * 8,
                            p_lds + (size_t)(p * 132 + 1 + half * 64) * 16);
            }
        }
        // ---- halo granules g=0 (wc=w0-1) and g=129 (wc=w0+128), 24 total ----
        if (tid < 24) {
            const int p = tid >> 1, side = tid & 1;
            const int row = p >> 1, kg = p & 1;
            const int hh = h0 - 1 + row;
            const int wc = side ? (w0 + 128) : (w0 - 1);
            int4 v = make_int4(0, 0, 0, 0);
            if (hh >= 0 && hh < 512 && wc >= 0 && wc < 512)
                v = *(const int4*)(inp + ((size_t)hh * 512 + wc) * 32 + (cb8 + kg) * 8);
            *(int4*)(p_lds + (size_t)(p * 132 + (side ? 129 : 0)) * 16) = v;
        }
        // ---- out-of-image rows: zero the whole plane pair (edge blocks only) ----
        if (h0 == 0) {
            for (int g = tid; g < 264; g += 512)
                *(int4*)(p_lds + (size_t)g * 16) = make_int4(0, 0, 0, 0);
        } else if (h0 == 508) {
            for (int g = tid; g < 264; g += 512)
                *(int4*)(p_lds + (size_t)(10 * 132 + g) * 16) = make_int4(0, 0, 0, 0);
        }
        __syncthreads();

        // ---- K-loop: 9 slots; 1 A-read feeds both ch MFMAs; kg = hi ----
#pragma unroll
        for (int s = 0; s < 9; ++s) {
            const int dh = s / 3, dwd = s % 3;
            const int row = rw + dh;
            short8 pf[2];
#pragma unroll
            for (int t4 = 0; t4 < 2; ++t4) {
                const int px = tq * 64 + t4 * 32 + dwd + lo5;
                pf[t4] = *(const short8*)(p_lds +
                    ((size_t)((row * 2 + hi) * 132 + px)) * 16);
            }
#pragma unroll
            for (int ch = 0; ch < 2; ++ch) {
                const short8 w8 = *(const short8*)(w_lds +
                    ((size_t)((ch * 9 + s) * 64 + l)) * 16);
#pragma unroll
                for (int t4 = 0; t4 < 2; ++t4)
                    acc[ch][t4] = __builtin_amdgcn_mfma_f32_32x32x16_bf16(
                        pf[t4], w8, acc[ch][t4], 0, 0, 0);
            }
        }
    }

    // ---- epilogue: D col = l&31 = co_local; 32 lanes = one pixel's contiguous 64 B ----
    const int h = h0 + rw;
#pragma unroll
    for (int ch = 0; ch < 2; ++ch) {
        const float bvs = bias[ch * 32 + lo5];
        const size_t pbase = ((size_t)(b * 2 + ch) * HWSZ + (size_t)h * 512);
#pragma unroll
        for (int t4 = 0; t4 < 2; ++t4) {
#pragma unroll
            for (int reg = 0; reg < 16; ++reg) {
                const int pxl = tq * 64 + t4 * 32 + (reg & 3) + 8 * (reg >> 2) + 4 * hi;
                const size_t o = (pbase + (w0 + pxl)) * 32 + lo5;
                float v = fmaxf(acc[ch][t4][reg] + bvs, 0.f);
                if (ADD_) v += bf2f(skip[o]);
                out[o] = f2bf(v);
            }
        }
    }
}

// ---------------- conv_last weight repack: A-operand fragment-linear, quarter-major ----------
__global__ __launch_bounds__(256)
void repackLn_k(const float* __restrict__ wsrc, unsigned short* __restrict__ d)
{
    const int t = blockIdx.x * 256 + threadIdx.x;   // < 18432
    const int j = t & 7, l = (t >> 3) & 63;
    const int rest = t >> 9;           // 0..35
    const int s = rest % 9, q = rest / 9;
    const int co = l & 31;
    const int ci = q * 16 + (l >> 5) * 8 + j;
    d[t] = (co < 30) ? f2bf(wsrc[((size_t)co * 64 + ci) * 9 + s]) : (unsigned short)0;
}

// ---------------- conv_last: 32x32x16 MFMA, A=weights(LDS) B=pixels(LDS), 4-phase ----------
__global__ __launch_bounds__(256)
void conv_lastN(const unsigned short* __restrict__ in,
                const unsigned short* __restrict__ wrp,
                unsigned short* __restrict__ out)
{
    extern __shared__ char smem[];
    char* w_lds = smem;              // 36864 B
    char* p_lds = smem + 36864;      // 16896 B

    const int id = blockIdx.x;                      // 2048 blocks
    const int lid = (id & 7) * 256 + (id >> 3);     // XCD chunk swizzle
    const int w0 = (lid & 3) * 128;
    const int h0 = ((lid >> 2) & 255) * 2;
    const int b  = lid >> 10;

    const int tid = threadIdx.x;
    const int wv = tid >> 6, l = tid & 63;
    const int rw = wv >> 1, tq = wv & 1;
    const int lo5 = l & 31, hi = l >> 5;

    f32x16 acc[2];
#pragma unroll
    for (int t4 = 0; t4 < 2; ++t4)
#pragma unroll
        for (int e = 0; e < 16; ++e) acc[t4][e] = 0.f;

    for (int q = 0; q < 4; ++q) {
        if (q) __syncthreads();

        const unsigned short* inp = in + (size_t)(b * 2 + (q >> 1)) * HWSZ * 32;
        const int cb8 = (q & 1) * 2;

        if (q == 0)
            for (int i = wv; i < 36; i += 4)
                gload16(wrp + (size_t)i * 512 + l * 8, w_lds + (size_t)i * 1024);
        for (int i = wv; i < 16; i += 4) {
            const int p = i >> 1, half = i & 1;
            const int row = p >> 1, kg = p & 1;
            const int hh = h0 - 1 + row;
            if (hh >= 0 && hh < 512)
                gload16(inp + ((size_t)hh * 512 + w0 + half * 64 + l) * 32 + (cb8 + kg) * 8,
                        p_lds + (size_t)(p * 132 + 1 + half * 64) * 16);
        }
        if (tid < 16) {
            const int p = tid >> 1, side = tid & 1;
            const int row = p >> 1, kg = p & 1;
            const int hh = h0 - 1 + row;
            const int wc = side ? (w0 + 128) : (w0 - 1);
            int4 v = make_int4(0, 0, 0, 0);
            if (hh >= 0 && hh < 512 && wc >= 0 && wc < 512)
                v = *(const int4*)(inp + ((size_t)hh * 512 + wc) * 32 + (cb8 + kg) * 8);
            *(int4*)(p_lds + (size_t)(p * 132 + (side ? 129 : 0)) * 16) = v;
        }
        if (h0 == 0) {
            for (int g = tid; g < 264; g += 256)
                *(int4*)(p_lds + (size_t)g * 16) = make_int4(0, 0, 0, 0);
        } else if (h0 == 510) {
            for (int g = tid; g < 264; g += 256)
                *(int4*)(p_lds + (size_t)(6 * 132 + g) * 16) = make_int4(0, 0, 0, 0);
        }
        __syncthreads();

#pragma unroll
        for (int s = 0; s < 9; ++s) {
            const int dh = s / 3, dwd = s % 3;
            const int row = rw + dh;
            const short8 wf = *(const short8*)(w_lds + ((size_t)((q * 9 + s) * 64 + l)) * 16);
#pragma unroll
            for (int t4 = 0; t4 < 2; ++t4) {
                const int px = tq * 64 + t4 * 32 + dwd + lo5;
                const short8 pf = *(const short8*)(p_lds +
                    ((size_t)((row * 2 + hi) * 132 + px)) * 16);
                acc[t4] = __builtin_amdgcn_mfma_f32_32x32x16_bf16(wf, pf, acc[t4], 0, 0, 0);
            }
        }
    }

    const int h = h0 + rw;
#pragma unroll
    for (int t4 = 0; t4 < 2; ++t4) {
        const int px = w0 + tq * 64 + t4 * 32 + lo5;
#pragma unroll
        for (int reg = 0; reg < 16; ++reg) {
            const int co = (reg & 3) + 8 * (reg >> 2) + 4 * hi;
            if (co < 30)
                out[(((size_t)(b * 30 + co) * 512 + h) * 512) + px] = f2bf(acc[t4][reg]);
        }
    }
}

// ---------------- fused adaptive filter ----------------
__global__ __launch_bounds__(256)
void filt_fused_k(const unsigned short* __restrict__ wl, const float* __restrict__ base,
                  float* __restrict__ out)
{
    __shared__ float F[516];

    const int id = blockIdx.x;                      // 3072 blocks
    const int lid = (id & 7) * 384 + (id >> 3);
    const int h = lid & 511;
    const int bc = lid >> 9;
    const int b = bc / 3, c = bc % 3;
    const int t = threadIdx.x;

    if (t < 2) F[t] = 0.f;
    if (t >= 254) F[t + 260] = 0.f;

    const size_t rowoff = (size_t)h * 512;
    const unsigned short* wv_p = wl + ((size_t)(b * 30 + c * 10) * HWSZ) + rowoff;
    const unsigned short* wh_p = wv_p + 5 * HWSZ;
    const float* bp = base + (size_t)bc * HWSZ;

#pragma unroll
    for (int wi = 0; wi < 2; ++wi) {
        const int w = t + wi * 256;
        float v[5]; float mx = -1e30f;
#pragma unroll
        for (int i = 0; i < 5; ++i) { v[i] = bf2f(wv_p[(size_t)i * HWSZ + w]); mx = fmaxf(mx, v[i]); }
        float sm = 0.f;
#pragma unroll
        for (int i = 0; i < 5; ++i) { v[i] = __expf(v[i] - mx); sm += v[i]; }
        const float inv = 1.f / sm;
        float acc = 0.f;
#pragma unroll
        for (int i = 0; i < 5; ++i) {
            const int hh = h + i - 2;
            const float bvv = (hh >= 0 && hh < 512) ? bp[(size_t)hh * 512 + w] : 0.f;
            acc = fmaf(bvv, v[i] * inv, acc);
        }
        F[w + 2] = acc;
    }
    __syncthreads();

#pragma unroll
    for (int wi = 0; wi < 2; ++wi) {
        const int w = t + wi * 256;
        float v[5]; float mx = -1e30f;
#pragma unroll
        for (int i = 0; i < 5; ++i) { v[i] = bf2f(wh_p[(size_t)i * HWSZ + w]); mx = fmaxf(mx, v[i]); }
        float sm = 0.f;
#pragma unroll
        for (int i = 0; i < 5; ++i) { v[i] = __expf(v[i] - mx); sm += v[i]; }
        const float inv = 1.f / sm;
        float acc = 0.f;
#pragma unroll
        for (int i = 0; i < 5; ++i)
            acc = fmaf(F[w + i], v[i] * inv, acc);
        out[(size_t)bc * HWSZ + rowoff + w] = acc;
    }
}

extern "C" void kernel_launch(void* const* d_in, const int* in_sizes, int n_in,
                              void* d_out, int out_size, void* d_ws, size_t ws_size,
                              hipStream_t stream)
{
    const float* fm      = (const float*)d_in[0];
    const float* base    = (const float*)d_in[1];
    const float* w_first = (const float*)d_in[2];
    const float* kb_w1   = (const float*)d_in[3];
    const float* kb_g1   = (const float*)d_in[4];
    const float* kb_b1   = (const float*)d_in[5];
    const float* kb_m1   = (const float*)d_in[6];
    const float* kb_v1   = (const float*)d_in[7];
    const float* kb_w2   = (const float*)d_in[8];
    const float* kb_g2   = (const float*)d_in[9];
    const float* kb_b2   = (const float*)d_in[10];
    const float* kb_m2   = (const float*)d_in[11];
    const float* kb_v2   = (const float*)d_in[12];
    const float* w_last  = (const float*)d_in[13];

    char* ws = (char*)d_ws;
    unsigned short* wrp3n  = (unsigned short*)ws;                 // 8*36864 bf16 = 589824 B
    unsigned short* wrpL   = wrp3n + (size_t)8 * 36864;           // 36864 B
    unsigned short* wrp7hi = wrpL + 18432;                        // 53248 B
    unsigned short* wrp7lo = wrp7hi + 26624;                      // 53248 B
    float*          biasws = (float*)(wrp7lo + 26624);            // 2048 B
    unsigned short* actA = (unsigned short*)(ws + (1 << 20));     // 67 MB each, split-plane NHWC32
    unsigned short* actB = actA + (size_t)2 * HWSZ * 64;
    unsigned short* actC = actB + (size_t)2 * HWSZ * 64;
    unsigned short* in7hi = actB;                                 // dead once conv7 done
    unsigned short* in7lo = actB + (size_t)2 * HWSZ * 8;
    unsigned short* logits = actC;                                // planar30; actC free by then

    hipFuncSetAttribute((const void*)conv3_mfma32<false>,
                        hipFuncAttributeMaxDynamicSharedMemorySize, 43776);
    hipFuncSetAttribute((const void*)conv3_mfma32<true>,
                        hipFuncAttributeMaxDynamicSharedMemorySize, 43776);
    hipFuncSetAttribute((const void*)conv_lastN,
                        hipFuncAttributeMaxDynamicSharedMemorySize, 53760);
    hipFuncSetAttribute((const void*)conv7_mfma,
                        hipFuncAttributeMaxDynamicSharedMemorySize, 50688);

    dim3 blk(256);

    // weight repacks + input prep
    repack3n_k<<<dim3(144, 1, 8), blk, 0, stream>>>(kb_w1, kb_w2, kb_g1, kb_v1, kb_g2, kb_v2, wrp3n);
    bias8_k<<<dim3(2, 1, 1), blk, 0, stream>>>(kb_g1, kb_b1, kb_m1, kb_v1, kb_g2, kb_b2, kb_m2, kb_v2, biasws);
    repackLn_k<<<dim3(72, 1, 1), blk, 0, stream>>>(w_last, wrpL);
    repack7_k<<<dim3(104, 1, 1), blk, 0, stream>>>(w_first, wrp7hi, wrp7lo);
    prep7_k<<<dim3(2048, 1, 1), blk, 0, stream>>>(fm, in7hi, in7lo);

    // conv_first -> actA (R12-recipe staging)
    conv7_mfma<<<dim3(2048, 1, 1), blk, 50688, stream>>>(in7hi, in7lo, wrp7hi, wrp7lo, actA);

    // residual blocks (R13 config: 32x32x16, ci-quarter 4-phase, global_load_lds staging)
    unsigned short* cur = actA;
    unsigned short* oth = actC;
    for (int i = 0; i < 4; ++i) {
        conv3_mfma32<false><<<dim3(1024, 1, 1), dim3(512), 43776, stream>>>(
            cur, wrp3n + (size_t)i * 36864, biasws + i * 64, nullptr, actB);
        conv3_mfma32<true><<<dim3(1024, 1, 1), dim3(512), 43776, stream>>>(
            actB, wrp3n + (size_t)(4 + i) * 36864, biasws + (4 + i) * 64, cur, oth);
        unsigned short* t = cur; cur = oth; oth = t;
    }

    // conv_last: 64 -> 30, planar30 bf16 logits
    conv_lastN<<<dim3(2048, 1, 1), blk, 53760, stream>>>(cur, wrpL, logits);

    // fused adaptive filtering
    filt_fused_k<<<dim3(3072, 1, 1), blk, 0, stream>>>(logits, base, (float*)d_out);
}